// Round 1
// baseline (1522.546 us; speedup 1.0000x reference)
//
#include <hip/hip_runtime.h>
#include <math.h>

#define BATCH 4096
#define L0 117
#define L1 234
#define L2 468
#define L3 937
#define L4 1875
#define L5 3750
#define JC 512
#define NTAB (L1 + L2 + L3 + L4 + L5)   // 7264 table entries

static __device__ __forceinline__ float lrelu(float v) { return v >= 0.f ? v : 0.2f * v; }

// ---------------------------------------------------------------- setup ----
// Rebuilds bicubic tables + zeroes stats every launch (ws is re-poisoned).
__global__ void k_setup(double* __restrict__ stats, int* __restrict__ ti0,
                        float4* __restrict__ tw)
{
    int s = blockIdx.x;                       // 0..4 -> stage s+1
    if (s == 0 && threadIdx.x < 96) stats[threadIdx.x] = 0.0;
    const int Lin[5]  = {L0, L1, L2, L3, L4};
    const int Lout[5] = {L1, L2, L3, L4, L5};
    const int Toff[5] = {0, L1, L1 + L2, L1 + L2 + L3, L1 + L2 + L3 + L4};
    int li = Lin[s], lo = Lout[s], off = Toff[s];
    float scale = (float)((double)li / (double)lo);
    const float A = -0.75f;
    for (int j = threadIdx.x; j < lo; j += blockDim.x) {
        float src = ((float)j + 0.5f) * scale - 0.5f;
        float fi = floorf(src);
        float t = src - fi;
        float u;
        float4 w;
        u = t + 1.f; w.x = ((A * u - 5.f * A) * u + 8.f * A) * u - 4.f * A;
        u = t;       w.y = ((A + 2.f) * u - (A + 3.f)) * u * u + 1.f;
        u = 1.f - t; w.z = ((A + 2.f) * u - (A + 3.f)) * u * u + 1.f;
        u = 2.f - t; w.w = ((A * u - 5.f * A) * u + 8.f * A) * u - 4.f * A;
        ti0[off + j] = (int)fi;     // can be -1 at j=0; clamped per tap later
        tw[off + j] = w;
    }
}

// ------------------------------------------------- input GEMM + bn0 stats ----
// oi[b][i] = x[b][:]·Wi[i][:] + bi[i]; accumulate sum/sumsq of all elements.
__global__ __launch_bounds__(256) void k0a(const float* __restrict__ x,
                                           const float* __restrict__ Wi,
                                           const float* __restrict__ bi,
                                           float* __restrict__ oi,
                                           double* __restrict__ stats)
{
    __shared__ float As[32][68];    // [k][m], padded
    __shared__ float Bs[32][132];   // [k][n], padded
    __shared__ float red[512];
    int m0 = blockIdx.y * 64;
    int n0 = blockIdx.x * 128;
    int tid = threadIdx.x;
    int tm = tid >> 4, tn = tid & 15;   // 16x16 thread grid, micro 4x8
    float acc[4][8];
#pragma unroll
    for (int r = 0; r < 4; r++)
#pragma unroll
        for (int c = 0; c < 8; c++) acc[r][c] = 0.f;

    for (int k0 = 0; k0 < 160; k0 += 32) {
        for (int e = tid; e < 64 * 32; e += 256) {
            int m = e >> 5, k = e & 31;
            As[k][m] = x[(size_t)(m0 + m) * 160 + k0 + k];
        }
        for (int e = tid; e < 128 * 32; e += 256) {
            int n = e >> 5, k = e & 31;
            int row = n0 + n;
            Bs[k][n] = (row < 936) ? Wi[(size_t)row * 160 + k0 + k] : 0.f;
        }
        __syncthreads();
#pragma unroll
        for (int k = 0; k < 32; k++) {
            float4 av = *(const float4*)&As[k][tm * 4];
            float4 bv0 = *(const float4*)&Bs[k][tn * 8];
            float4 bv1 = *(const float4*)&Bs[k][tn * 8 + 4];
            float a[4] = {av.x, av.y, av.z, av.w};
            float b[8] = {bv0.x, bv0.y, bv0.z, bv0.w, bv1.x, bv1.y, bv1.z, bv1.w};
#pragma unroll
            for (int r = 0; r < 4; r++)
#pragma unroll
                for (int c = 0; c < 8; c++) acc[r][c] = fmaf(a[r], b[c], acc[r][c]);
        }
        __syncthreads();
    }
    float lsum = 0.f, lsq = 0.f;
#pragma unroll
    for (int r = 0; r < 4; r++) {
        int row = m0 + tm * 4 + r;
        int col = n0 + tn * 8;
        float vals[8];
#pragma unroll
        for (int c = 0; c < 8; c++) {
            float v = (col + c < 936) ? acc[r][c] + bi[col + c] : 0.f;
            vals[c] = v;
            lsum += v;
            lsq += v * v;
        }
        if (col + 7 < 936) {
            *(float4*)&oi[(size_t)row * 936 + col] = make_float4(vals[0], vals[1], vals[2], vals[3]);
            *(float4*)&oi[(size_t)row * 936 + col + 4] = make_float4(vals[4], vals[5], vals[6], vals[7]);
        } else {
            for (int c = 0; c < 8; c++)
                if (col + c < 936) oi[(size_t)row * 936 + col + c] = vals[c];
        }
    }
    red[tid] = lsum;
    red[256 + tid] = lsq;
    __syncthreads();
    for (int s2 = 128; s2 > 0; s2 >>= 1) {
        if (tid < s2) { red[tid] += red[tid + s2]; red[256 + tid] += red[256 + tid + s2]; }
        __syncthreads();
    }
    if (tid == 0) {
        atomicAdd(&stats[0], (double)red[0]);
        atomicAdd(&stats[8], (double)red[256]);
    }
}

// ------------------------------------- bn0 apply + class branch -> h0 ----
// h0 layout [B][117][9] channel-last; channel 8 = class branch.
__global__ __launch_bounds__(128) void k0b(const float* __restrict__ oi,
                                           const float* __restrict__ emb,
                                           const int* __restrict__ y,
                                           const float* __restrict__ Wc,
                                           const float* __restrict__ bc,
                                           const float* __restrict__ g0,
                                           const float* __restrict__ b0,
                                           const double* __restrict__ stats,
                                           float* __restrict__ h0)
{
    __shared__ float embs[50];
    __shared__ float sa, sc;
    int b = blockIdx.x;
    int tid = threadIdx.x;
    if (tid < 50) embs[tid] = emb[y[b] * 50 + tid];
    if (tid == 0) {
        double N = (double)BATCH * 936.0;
        double m = stats[0] / N;
        double var = stats[8] / N - m * m;
        double a = (double)g0[0] / sqrt(var + 1e-5);
        sa = (float)a;
        sc = (float)((double)b0[0] - m * a);
    }
    __syncthreads();
    int l = tid;
    if (l < 117) {
        float oc = bc[l];
        for (int k = 0; k < 50; k++) oc = fmaf(embs[k], Wc[l * 50 + k], oc);
        float* dst = &h0[((size_t)b * 117 + l) * 9];
#pragma unroll
        for (int c = 0; c < 8; c++) {
            float v = oi[(size_t)b * 936 + c * 117 + l];
            dst[c] = lrelu(fmaf(v, sa, sc));
        }
        dst[8] = oc;
    }
}

// ------------------------------------------------- generic stage kernel ----
// Computes z = up(W·h_in) per chunk (conv commuted to input resolution).
// APPLY: h_out = lrelu(bn(z)) written [B][Lout][8].  !APPLY: accumulate z stats.
template <int CIN, bool APPLY>
__global__ __launch_bounds__(256) void k_stage(const float* __restrict__ hin,
                                               float* __restrict__ hout,
                                               const float* __restrict__ W,
                                               const float* __restrict__ g,
                                               const float* __restrict__ bpar,
                                               double* __restrict__ stats,
                                               const int* __restrict__ ti0,
                                               const float4* __restrict__ tw,
                                               int Lin, int Lout, int nchunk, int total)
{
    __shared__ float Ws[8 * CIN];
    __shared__ float vv[264][10];
    __shared__ float aa[8], cc[8];
    __shared__ float red[4][16];
    int tid = threadIdx.x;
    if (tid < 8 * CIN) Ws[tid] = W[tid];
    if constexpr (APPLY) {
        if (tid < 8) {
            double N = (double)BATCH * (double)Lout;
            double m = stats[tid] / N;
            double var = stats[8 + tid] / N - m * m;
            double a = (double)g[tid] / sqrt(var + 1e-5);
            aa[tid] = (float)a;
            cc[tid] = (float)((double)bpar[tid] - m * a);
        }
    }
    float ls[8], lq[8];
    if constexpr (!APPLY) {
#pragma unroll
        for (int o = 0; o < 8; o++) { ls[o] = 0.f; lq[o] = 0.f; }
    }
    __syncthreads();

    for (int idx = blockIdx.x; idx < total; idx += gridDim.x) {
        int b = idx / nchunk, ch = idx - b * nchunk;
        int j0 = ch * JC;
        int j1 = min(j0 + JC, Lout);
        int qlo = max(0, ti0[j0] - 1);
        int qhi = min(Lin - 1, ti0[j1 - 1] + 2);
        int NQ = qhi - qlo + 1;
        // phase 1: v[q][o] = sum_c W[o][c] * h[b][qlo+q][c]
        for (int q = tid; q < NQ; q += 256) {
            const float* hp = hin + ((size_t)b * Lin + qlo + q) * CIN;
            float h[CIN];
#pragma unroll
            for (int c = 0; c < CIN; c++) h[c] = hp[c];
#pragma unroll
            for (int o = 0; o < 8; o++) {
                float acc = 0.f;
#pragma unroll
                for (int c = 0; c < CIN; c++) acc = fmaf(Ws[o * CIN + c], h[c], acc);
                vv[q][o] = acc;
            }
        }
        __syncthreads();
        // phase 2: z[j][o] = sum_k w_k * v[tap_k][o]
        for (int j = j0 + tid; j < j1; j += 256) {
            int i0 = ti0[j];
            float4 w = tw[j];
            float wk[4] = {w.x, w.y, w.z, w.w};
            float z[8] = {0.f, 0.f, 0.f, 0.f, 0.f, 0.f, 0.f, 0.f};
#pragma unroll
            for (int k = 0; k < 4; k++) {
                int qq = min(max(i0 - 1 + k, 0), Lin - 1) - qlo;
                const float* vp = vv[qq];
#pragma unroll
                for (int o = 0; o < 8; o++) z[o] = fmaf(wk[k], vp[o], z[o]);
            }
            if constexpr (APPLY) {
                float rr[8];
#pragma unroll
                for (int o = 0; o < 8; o++) rr[o] = lrelu(fmaf(z[o], aa[o], cc[o]));
                float* dst = &hout[((size_t)b * Lout + j) * 8];
                *(float4*)dst = make_float4(rr[0], rr[1], rr[2], rr[3]);
                *(float4*)(dst + 4) = make_float4(rr[4], rr[5], rr[6], rr[7]);
            } else {
#pragma unroll
                for (int o = 0; o < 8; o++) { ls[o] += z[o]; lq[o] += z[o] * z[o]; }
            }
        }
        __syncthreads();
    }

    if constexpr (!APPLY) {
#pragma unroll
        for (int o = 0; o < 8; o++) {
            for (int off = 32; off > 0; off >>= 1) {
                ls[o] += __shfl_down(ls[o], off, 64);
                lq[o] += __shfl_down(lq[o], off, 64);
            }
        }
        int wave = tid >> 6, lane = tid & 63;
        if (lane == 0) {
#pragma unroll
            for (int o = 0; o < 8; o++) { red[wave][o] = ls[o]; red[wave][8 + o] = lq[o]; }
        }
        __syncthreads();
        if (tid < 16) {
            float v = red[0][tid] + red[1][tid] + red[2][tid] + red[3][tid];
            atomicAdd(&stats[tid], (double)v);
        }
    }
}

// ------------------------------- 2-hop kernel: h3 -> (h4 fly) -> stage 5 ----
// APPLY: fuses bn5+lrelu+final conv -> writes d_out.  !APPLY: z5 stats.
template <bool APPLY>
__global__ __launch_bounds__(256) void k_2hop(const float* __restrict__ h3,
                                              float* __restrict__ dout,
                                              const float* __restrict__ W4,
                                              const float* __restrict__ W5,
                                              const float* __restrict__ w6,
                                              const float* __restrict__ g4,
                                              const float* __restrict__ b4,
                                              const float* __restrict__ g5,
                                              const float* __restrict__ b5,
                                              double* __restrict__ stats,
                                              const int* __restrict__ ti04,
                                              const float4* __restrict__ tw4,
                                              const int* __restrict__ ti05,
                                              const float4* __restrict__ tw5,
                                              int total)
{
    __shared__ float W4s[64], W5s[64], w6s[8];
    __shared__ float v4[144][10];
    __shared__ float v5[264][10];
    __shared__ float a4[8], c4[8], a5[8], c5[8];
    __shared__ float red[4][16];
    int tid = threadIdx.x;
    if (tid < 64) { W4s[tid] = W4[tid]; W5s[tid] = W5[tid]; }
    if (tid < 8) {
        w6s[tid] = w6[tid];
        const double* st4 = stats + 64;
        double N4 = (double)BATCH * (double)L4;
        double m = st4[tid] / N4;
        double var = st4[8 + tid] / N4 - m * m;
        double a = (double)g4[tid] / sqrt(var + 1e-5);
        a4[tid] = (float)a;
        c4[tid] = (float)((double)b4[tid] - m * a);
        if constexpr (APPLY) {
            const double* st5 = stats + 80;
            double N5 = (double)BATCH * (double)L5;
            double m5 = st5[tid] / N5;
            double var5 = st5[8 + tid] / N5 - m5 * m5;
            double a5v = (double)g5[tid] / sqrt(var5 + 1e-5);
            a5[tid] = (float)a5v;
            c5[tid] = (float)((double)b5[tid] - m5 * a5v);
        }
    }
    float ls[8], lq[8];
    if constexpr (!APPLY) {
#pragma unroll
        for (int o = 0; o < 8; o++) { ls[o] = 0.f; lq[o] = 0.f; }
    }
    __syncthreads();

    const int nchunk = (L5 + JC - 1) / JC;  // 8
    for (int idx = blockIdx.x; idx < total; idx += gridDim.x) {
        int b = idx / nchunk, ch = idx - b * nchunk;
        int j0 = ch * JC;
        int j1 = min(j0 + JC, L5);
        int plo = max(0, ti05[j0] - 1);
        int phi = min(L4 - 1, ti05[j1 - 1] + 2);
        int NP = phi - plo + 1;
        int qlo = max(0, ti04[plo] - 1);
        int qhi = min(L3 - 1, ti04[phi] + 2);
        int NQ = qhi - qlo + 1;
        // phase 1: v4 = W4·h3
        for (int q = tid; q < NQ; q += 256) {
            const float4* hp = (const float4*)(h3 + ((size_t)b * L3 + qlo + q) * 8);
            float4 hA = hp[0], hB = hp[1];
            float h[8] = {hA.x, hA.y, hA.z, hA.w, hB.x, hB.y, hB.z, hB.w};
#pragma unroll
            for (int o = 0; o < 8; o++) {
                float acc = 0.f;
#pragma unroll
                for (int c = 0; c < 8; c++) acc = fmaf(W4s[o * 8 + c], h[c], acc);
                v4[q][o] = acc;
            }
        }
        __syncthreads();
        // phase 2: h4 = lrelu(bn4(up(v4))), v5 = W5·h4 (kept in LDS)
        for (int p = tid; p < NP; p += 256) {
            int i0 = ti04[plo + p];
            float4 w = tw4[plo + p];
            float wk[4] = {w.x, w.y, w.z, w.w};
            float z[8] = {0.f, 0.f, 0.f, 0.f, 0.f, 0.f, 0.f, 0.f};
#pragma unroll
            for (int k = 0; k < 4; k++) {
                int qq = min(max(i0 - 1 + k, 0), L3 - 1) - qlo;
                const float* vp = v4[qq];
#pragma unroll
                for (int o = 0; o < 8; o++) z[o] = fmaf(wk[k], vp[o], z[o]);
            }
            float h4v[8];
#pragma unroll
            for (int o = 0; o < 8; o++) h4v[o] = lrelu(fmaf(z[o], a4[o], c4[o]));
#pragma unroll
            for (int o = 0; o < 8; o++) {
                float acc = 0.f;
#pragma unroll
                for (int c = 0; c < 8; c++) acc = fmaf(W5s[o * 8 + c], h4v[c], acc);
                v5[p][o] = acc;
            }
        }
        __syncthreads();
        // phase 3: z5 = up(v5); then stats or bn5+lrelu+final conv
        for (int j = j0 + tid; j < j1; j += 256) {
            int i0 = ti05[j];
            float4 w = tw5[j];
            float wk[4] = {w.x, w.y, w.z, w.w};
            float z[8] = {0.f, 0.f, 0.f, 0.f, 0.f, 0.f, 0.f, 0.f};
#pragma unroll
            for (int k = 0; k < 4; k++) {
                int pp = min(max(i0 - 1 + k, 0), L4 - 1) - plo;
                const float* vp = v5[pp];
#pragma unroll
                for (int o = 0; o < 8; o++) z[o] = fmaf(wk[k], vp[o], z[o]);
            }
            if constexpr (APPLY) {
                float r = 0.f;
#pragma unroll
                for (int o = 0; o < 8; o++) {
                    float h5 = lrelu(fmaf(z[o], a5[o], c5[o]));
                    r = fmaf(w6s[o], h5, r);
                }
                dout[(size_t)b * L5 + j] = r;
            } else {
#pragma unroll
                for (int o = 0; o < 8; o++) { ls[o] += z[o]; lq[o] += z[o] * z[o]; }
            }
        }
        __syncthreads();
    }

    if constexpr (!APPLY) {
#pragma unroll
        for (int o = 0; o < 8; o++) {
            for (int off = 32; off > 0; off >>= 1) {
                ls[o] += __shfl_down(ls[o], off, 64);
                lq[o] += __shfl_down(lq[o], off, 64);
            }
        }
        int wave = tid >> 6, lane = tid & 63;
        if (lane == 0) {
#pragma unroll
            for (int o = 0; o < 8; o++) { red[wave][o] = ls[o]; red[wave][8 + o] = lq[o]; }
        }
        __syncthreads();
        if (tid < 16) {
            float v = red[0][tid] + red[1][tid] + red[2][tid] + red[3][tid];
            atomicAdd(&stats[80 + tid], (double)v);
        }
    }
}

// ---------------------------------------------------------------- launch ----
extern "C" void kernel_launch(void* const* d_in, const int* in_sizes, int n_in,
                              void* d_out, int out_size, void* d_ws, size_t ws_size,
                              hipStream_t stream)
{
    const float* x   = (const float*)d_in[0];
    const int*   y   = (const int*)d_in[1];
    const float* emb = (const float*)d_in[2];
    const float* Wc  = (const float*)d_in[3];
    const float* bc  = (const float*)d_in[4];
    const float* Wi  = (const float*)d_in[5];
    const float* bi  = (const float*)d_in[6];
    const float* g0  = (const float*)d_in[7];
    const float* b0  = (const float*)d_in[8];
    const float* w1  = (const float*)d_in[9];
    const float* w2  = (const float*)d_in[10];
    const float* w3  = (const float*)d_in[11];
    const float* w4  = (const float*)d_in[12];
    const float* w5  = (const float*)d_in[13];
    const float* w6  = (const float*)d_in[14];
    const float* g1  = (const float*)d_in[15];
    const float* b1  = (const float*)d_in[16];
    const float* g2  = (const float*)d_in[17];
    const float* b2  = (const float*)d_in[18];
    const float* g3  = (const float*)d_in[19];
    const float* b3  = (const float*)d_in[20];
    const float* g4  = (const float*)d_in[21];
    const float* b4  = (const float*)d_in[22];
    const float* g5  = (const float*)d_in[23];
    const float* b5  = (const float*)d_in[24];
    float* out = (float*)d_out;

    char* ws = (char*)d_ws;
    size_t off = 0;
    auto alloc = [&](size_t bytes) {
        size_t r = off;
        off += (bytes + 255) & ~(size_t)255;
        return r;
    };
    double* stats = (double*)(ws + alloc(96 * sizeof(double)));
    int*    ti0   = (int*)(ws + alloc((size_t)NTAB * sizeof(int)));
    float4* tw    = (float4*)(ws + alloc((size_t)NTAB * sizeof(float4)));
    float*  oi    = (float*)(ws + alloc((size_t)BATCH * 936 * 4));
    float*  h0    = (float*)(ws + alloc((size_t)BATCH * L0 * 9 * 4));
    float*  h1    = (float*)(ws + alloc((size_t)BATCH * L1 * 8 * 4));
    float*  h2    = (float*)(ws + alloc((size_t)BATCH * L2 * 8 * 4));
    float*  h3    = (float*)(ws + alloc((size_t)BATCH * L3 * 8 * 4));

    const int T1 = 0, T2 = L1, T3 = L1 + L2, T4 = L1 + L2 + L3, T5 = L1 + L2 + L3 + L4;
    const int GS = 512;  // stats grids: keeps per-address f64 atomic depth ~512

    k_setup<<<5, 256, 0, stream>>>(stats, ti0, tw);
    k0a<<<dim3(8, 64), 256, 0, stream>>>(x, Wi, bi, oi, stats);
    k0b<<<BATCH, 128, 0, stream>>>(oi, emb, y, Wc, bc, g0, b0, stats, h0);
    // stage 1 (CIN=9): 117 -> 234
    k_stage<9, false><<<GS, 256, 0, stream>>>(h0, nullptr, w1, nullptr, nullptr, stats + 16,
                                              ti0 + T1, tw + T1, L0, L1, 1, BATCH);
    k_stage<9, true><<<BATCH, 256, 0, stream>>>(h0, h1, w1, g1, b1, stats + 16,
                                                ti0 + T1, tw + T1, L0, L1, 1, BATCH);
    // stage 2: 234 -> 468
    k_stage<8, false><<<GS, 256, 0, stream>>>(h1, nullptr, w2, nullptr, nullptr, stats + 32,
                                              ti0 + T2, tw + T2, L1, L2, 1, BATCH);
    k_stage<8, true><<<BATCH, 256, 0, stream>>>(h1, h2, w2, g2, b2, stats + 32,
                                                ti0 + T2, tw + T2, L1, L2, 1, BATCH);
    // stage 3: 468 -> 937 (2 chunks)
    k_stage<8, false><<<GS, 256, 0, stream>>>(h2, nullptr, w3, nullptr, nullptr, stats + 48,
                                              ti0 + T3, tw + T3, L2, L3, 2, BATCH * 2);
    k_stage<8, true><<<BATCH * 2, 256, 0, stream>>>(h2, h3, w3, g3, b3, stats + 48,
                                                    ti0 + T3, tw + T3, L2, L3, 2, BATCH * 2);
    // stage 4 stats only: 937 -> 1875 (4 chunks); h4 never materialized
    k_stage<8, false><<<GS, 256, 0, stream>>>(h3, nullptr, w4, nullptr, nullptr, stats + 64,
                                              ti0 + T4, tw + T4, L3, L4, 4, BATCH * 4);
    // stage 5 two-hop: h3 -> h4 (fly) -> z5 stats, then apply + final conv
    k_2hop<false><<<GS, 256, 0, stream>>>(h3, nullptr, w4, w5, w6, g4, b4, g5, b5, stats,
                                          ti0 + T4, tw + T4, ti0 + T5, tw + T5, BATCH * 8);
    k_2hop<true><<<BATCH * 8, 256, 0, stream>>>(h3, out, w4, w5, w6, g4, b4, g5, b5, stats,
                                                ti0 + T4, tw + T4, ti0 + T5, tw + T5, BATCH * 8);
}